// Round 2
// baseline (448.986 us; speedup 1.0000x reference)
//
#include <hip/hip_runtime.h>
#include <hip/hip_bf16.h>

// HybridSelfAttention: out = softmax((xWq)(xWk)^T / sqrt(d)) (xWv)
// B=4, S=2048, D=1024, fp32 in/out.
//
// Precision: f16 hi/lo split + 3-product MFMA for xWq, xWk, QK^T (softmax is
// near-one-hot; S must be ~fp32-accurate). Plain f16 MFMA for V and PV.
//
// R1 change: LDS chunk swizzle. Tile rows are 64B (4x16B chunks); unswizzled
// ds_read_b128 hits bank-groups (4r+q)%8 -> 4-way conflict per 8-lane phase
// (8.4M conflict cycles on the S-GEMM). Store logical chunk c of row r at
// physical chunk p=(c+(r>>1))&3; reads become conflict-free. Compatible with
// global_load_lds (we permute which global chunk each thread fetches, not the
// LDS destination).

typedef _Float16 half8 __attribute__((ext_vector_type(8)));
typedef _Float16 half4v __attribute__((ext_vector_type(4)));
typedef float f32x4 __attribute__((ext_vector_type(4)));

#define GLOBAL_AS __attribute__((address_space(1)))
#define LDS_AS __attribute__((address_space(3)))

__device__ __forceinline__ void gll16(const _Float16* g, _Float16* l) {
    // async global->LDS, 16B per lane; LDS dest is wave-uniform base + lane*16
    __builtin_amdgcn_global_load_lds((GLOBAL_AS const void*)g, (LDS_AS void*)l, 16, 0, 0);
}

// ---------------------------------------------------------------------------
// NT GEMM: C[M,N] = (A0+A1)[M,K] * (B0+B1)[N,K]^T   (A,B row-major, K inner)
// NPROD: 1 = single product (A0*B0), 3 = split product (A0B0+A0B1+A1B0)
// OUTMODE: 0 = fp32 to Cf; 1 = f16 hi/lo split to C0,C1; 2 = f16 to C0
// Tiles: 128x128 per block (256 thr = 4 waves, 64x64 per wave), BK=32.
// mfma_f32_16x16x32_f16 fragments:
//   A/B frag: lane holds row (lane&15), 8 contiguous k at (lane>>4)*8
//   C/D frag: col = lane&15, row = (lane>>4)*4 + reg
// ---------------------------------------------------------------------------
template <int NPROD, int OUTMODE>
__global__ __launch_bounds__(256) void gemm_nt(
    const _Float16* __restrict__ A0, const _Float16* __restrict__ A1,
    const _Float16* __restrict__ B0, const _Float16* __restrict__ B1,
    float* __restrict__ Cf, _Float16* __restrict__ C0, _Float16* __restrict__ C1,
    int lda, int ldb, int ldc, int K,
    long sA, long sB, long sC, float scale) {
    constexpr int NTILES = (NPROD == 3) ? 4 : 2;
    __shared__ alignas(16) _Float16 smem[NTILES * 4096];  // [128][32] f16 tiles
    _Float16* sA0 = smem;
    _Float16* sB0 = smem + 4096;
    _Float16* sA1 = (NPROD == 3) ? smem + 8192 : smem;
    _Float16* sB1 = (NPROD == 3) ? smem + 12288 : smem;

    const int tid = threadIdx.x;
    const int wave = tid >> 6, lane = tid & 63;
    const int wm = (wave >> 1) * 64, wn = (wave & 1) * 64;
    const int quad = lane >> 4, r16 = lane & 15;

    const long zA = (long)blockIdx.z * sA;
    const long zB = (long)blockIdx.z * sB;
    const long zC = (long)blockIdx.z * sC;

    // staging: thread t stages 16B at LDS offset t*16 (row t>>2, phys chunk t&3).
    // Swizzle: phys chunk p holds logical chunk c = (p - (row>>1)) & 3.
    const int trow = tid >> 2;
    const int tcol = ((((tid & 3) - ((tid >> 3) & 3)) & 3)) * 8;
    const _Float16* gA0 = A0 + zA + (long)(blockIdx.x * 128 + trow) * lda + tcol;
    const _Float16* gB0 = B0 + zB + (long)(blockIdx.y * 128 + trow) * ldb + tcol;
    const _Float16* gA1 = (NPROD == 3) ? (A1 + zA + (long)(blockIdx.x * 128 + trow) * lda + tcol) : nullptr;
    const _Float16* gB1 = (NPROD == 3) ? (B1 + zB + (long)(blockIdx.y * 128 + trow) * ldb + tcol) : nullptr;

    f32x4 acc[4][4];
#pragma unroll
    for (int i = 0; i < 4; ++i)
#pragma unroll
        for (int j = 0; j < 4; ++j) {
            acc[i][j][0] = 0.f; acc[i][j][1] = 0.f; acc[i][j][2] = 0.f; acc[i][j][3] = 0.f;
        }

    const int ldsoff = tid * 8;  // halves; *2B = tid*16 bytes
    // read-side swizzle: physical chunk for logical chunk `quad` at row r:
    // p = (quad + (r>>1)) & 3; (r>>1)&3 reduces to (r16>>1)&3 here since
    // wm and i*16 contribute multiples of 4 to r>>1.
    const int p8 = ((quad + (r16 >> 1)) & 3) * 8;

    for (int k0 = 0; k0 < K; k0 += 32) {
        __syncthreads();  // previous iter's ds_reads done before overwrite
        gll16(gA0, sA0 + ldsoff);
        gll16(gA0 + 64 * lda, sA0 + ldsoff + 2048);
        gll16(gB0, sB0 + ldsoff);
        gll16(gB0 + 64 * ldb, sB0 + ldsoff + 2048);
        if (NPROD == 3) {
            gll16(gA1, sA1 + ldsoff);
            gll16(gA1 + 64 * lda, sA1 + ldsoff + 2048);
            gll16(gB1, sB1 + ldsoff);
            gll16(gB1 + 64 * ldb, sB1 + ldsoff + 2048);
        }
        gA0 += 32; gB0 += 32;
        if (NPROD == 3) { gA1 += 32; gB1 += 32; }
        __syncthreads();  // staging visible (compiler drains vmcnt before barrier)

        half8 a0[4], b0[4], a1[4], b1[4];
#pragma unroll
        for (int i = 0; i < 4; ++i) {
            a0[i] = *(const half8*)(sA0 + (wm + i * 16 + r16) * 32 + p8);
            b0[i] = *(const half8*)(sB0 + (wn + i * 16 + r16) * 32 + p8);
            if (NPROD == 3) {
                a1[i] = *(const half8*)(sA1 + (wm + i * 16 + r16) * 32 + p8);
                b1[i] = *(const half8*)(sB1 + (wn + i * 16 + r16) * 32 + p8);
            }
        }
#pragma unroll
        for (int i = 0; i < 4; ++i)
#pragma unroll
            for (int j = 0; j < 4; ++j) {
                acc[i][j] = __builtin_amdgcn_mfma_f32_16x16x32_f16(a0[i], b0[j], acc[i][j], 0, 0, 0);
                if (NPROD == 3) {
                    acc[i][j] = __builtin_amdgcn_mfma_f32_16x16x32_f16(a0[i], b1[j], acc[i][j], 0, 0, 0);
                    acc[i][j] = __builtin_amdgcn_mfma_f32_16x16x32_f16(a1[i], b0[j], acc[i][j], 0, 0, 0);
                }
            }
    }

    // epilogue: C/D layout col=lane&15, row=quad*4+reg
    const int crow0 = blockIdx.x * 128 + wm + quad * 4;
    const int ccol0 = blockIdx.y * 128 + wn + r16;
#pragma unroll
    for (int i = 0; i < 4; ++i)
#pragma unroll
        for (int j = 0; j < 4; ++j)
#pragma unroll
            for (int r = 0; r < 4; ++r) {
                long off = zC + (long)(crow0 + i * 16 + r) * ldc + (ccol0 + j * 16);
                float v = acc[i][j][r] * scale;
                if (OUTMODE == 0) {
                    Cf[off] = v;
                } else if (OUTMODE == 2) {
                    C0[off] = (_Float16)v;
                } else {
                    _Float16 h = (_Float16)v;
                    C0[off] = h;
                    C1[off] = (_Float16)(v - (float)h);
                }
            }
}

// ---------------------------------------------------------------------------
// x fp32 -> hi/lo f16 split (vectorized x4)
// ---------------------------------------------------------------------------
__global__ __launch_bounds__(256) void split_x(const float* __restrict__ in,
                                               _Float16* __restrict__ o0,
                                               _Float16* __restrict__ o1, long n4) {
    long i = (long)blockIdx.x * 256 + threadIdx.x;
    if (i >= n4) return;
    float4 v = ((const float4*)in)[i];
    float a[4] = {v.x, v.y, v.z, v.w};
    half4v h, l;
#pragma unroll
    for (int c = 0; c < 4; ++c) {
        h[c] = (_Float16)a[c];
        l[c] = (_Float16)(a[c] - (float)h[c]);
    }
    ((half4v*)o0)[i] = h;
    ((half4v*)o1)[i] = l;
}

// ---------------------------------------------------------------------------
// W[1024][1024] fp32 -> W^T hi/lo f16  (32x32 LDS tiles)
// ---------------------------------------------------------------------------
__global__ __launch_bounds__(256) void transpose_split_w(const float* __restrict__ in,
                                                         _Float16* __restrict__ o0,
                                                         _Float16* __restrict__ o1) {
    __shared__ float t[32][33];
    const int c0 = blockIdx.x * 32, r0 = blockIdx.y * 32;
    const int tx = threadIdx.x & 31, ty = threadIdx.x >> 5;
#pragma unroll
    for (int i = 0; i < 32; i += 8)
        t[ty + i][tx] = in[(long)(r0 + ty + i) * 1024 + c0 + tx];
    __syncthreads();
#pragma unroll
    for (int i = 0; i < 32; i += 8) {
        float v = t[tx][ty + i];
        _Float16 h = (_Float16)v;
        long o = (long)(c0 + ty + i) * 1024 + r0 + tx;
        o0[o] = h;
        o1[o] = (_Float16)(v - (float)h);
    }
}

// ---------------------------------------------------------------------------
// per-batch f16 transpose: in [R][C] -> out [C][R]
// ---------------------------------------------------------------------------
__global__ __launch_bounds__(256) void transpose_f16_k(const _Float16* __restrict__ in,
                                                       _Float16* __restrict__ out,
                                                       int R, int C, long sIn, long sOut) {
    __shared__ _Float16 t[32][33];
    const long bi = (long)blockIdx.z * sIn, bo = (long)blockIdx.z * sOut;
    const int c0 = blockIdx.x * 32, r0 = blockIdx.y * 32;
    const int tx = threadIdx.x & 31, ty = threadIdx.x >> 5;
#pragma unroll
    for (int i = 0; i < 32; i += 8)
        t[ty + i][tx] = in[bi + (long)(r0 + ty + i) * C + c0 + tx];
    __syncthreads();
#pragma unroll
    for (int i = 0; i < 32; i += 8)
        out[bo + (long)(c0 + ty + i) * R + r0 + tx] = t[tx][ty + i];
}

// ---------------------------------------------------------------------------
// row softmax: S fp32 [8192][2048] -> P f16, one block per row (vectorized)
// ---------------------------------------------------------------------------
__global__ __launch_bounds__(256) void softmax_rows(const float* __restrict__ S,
                                                    _Float16* __restrict__ P) {
    const int n = 2048;
    const long base = (long)blockIdx.x * n;
    const float4* row4 = (const float4*)(S + base);
    const int tid = threadIdx.x;
    const int wave = tid >> 6;

    float4 v0 = row4[tid * 2];
    float4 v1 = row4[tid * 2 + 1];
    float v[8] = {v0.x, v0.y, v0.z, v0.w, v1.x, v1.y, v1.z, v1.w};
    float lm = -3.4e38f;
#pragma unroll
    for (int t = 0; t < 8; ++t) lm = fmaxf(lm, v[t]);
#pragma unroll
    for (int o = 32; o > 0; o >>= 1) lm = fmaxf(lm, __shfl_xor(lm, o));
    __shared__ float redm[4];
    __shared__ float reds[4];
    if ((tid & 63) == 0) redm[wave] = lm;
    __syncthreads();
    lm = fmaxf(fmaxf(redm[0], redm[1]), fmaxf(redm[2], redm[3]));

    float e[8];
    float ls = 0.f;
#pragma unroll
    for (int t = 0; t < 8; ++t) {
        e[t] = __expf(v[t] - lm);
        ls += e[t];
    }
#pragma unroll
    for (int o = 32; o > 0; o >>= 1) ls += __shfl_xor(ls, o);
    if ((tid & 63) == 0) reds[wave] = ls;
    __syncthreads();
    ls = reds[0] + reds[1] + reds[2] + reds[3];
    const float inv = 1.f / ls;
    half8 p;
#pragma unroll
    for (int t = 0; t < 8; ++t) p[t] = (_Float16)(e[t] * inv);
    ((half8*)(P + base))[tid] = p;
}

// ---------------------------------------------------------------------------
extern "C" void kernel_launch(void* const* d_in, const int* in_sizes, int n_in,
                              void* d_out, int out_size, void* d_ws, size_t ws_size,
                              hipStream_t stream) {
    (void)in_sizes; (void)n_in; (void)out_size; (void)ws_size;
    const float* x = (const float*)d_in[0];
    const float* wq = (const float*)d_in[1];
    const float* wk = (const float*)d_in[2];
    const float* wv = (const float*)d_in[3];
    float* out = (float*)d_out;
    char* ws = (char*)d_ws;

    const long MB = 1l << 20;
    // ws layout (204 MB total):
    _Float16* Wq0 = (_Float16*)(ws + 0 * MB);
    _Float16* Wq1 = (_Float16*)(ws + 2 * MB);
    _Float16* Wk0 = (_Float16*)(ws + 4 * MB);
    _Float16* Wk1 = (_Float16*)(ws + 6 * MB);
    _Float16* Wv0 = (_Float16*)(ws + 8 * MB);
    _Float16* Wv1 = (_Float16*)(ws + 10 * MB);
    _Float16* x0 = (_Float16*)(ws + 12 * MB);   // 16 MB
    _Float16* x1 = (_Float16*)(ws + 28 * MB);   // 16 MB
    _Float16* P  = (_Float16*)(ws + 12 * MB);   // 32 MB, reuses dead x0/x1
    _Float16* Q0 = (_Float16*)(ws + 44 * MB);
    _Float16* Q1 = (_Float16*)(ws + 60 * MB);
    _Float16* K0 = (_Float16*)(ws + 76 * MB);
    _Float16* K1 = (_Float16*)(ws + 92 * MB);
    _Float16* V  = (_Float16*)(ws + 108 * MB);
    _Float16* Vt = (_Float16*)(ws + 124 * MB);
    float* S = (float*)(ws + 140 * MB);         // 64 MB

    const int B = 4, SEQ = 2048, D = 1024;
    const long M = (long)B * SEQ;  // 8192

    // 1) split x into f16 hi/lo
    split_x<<<dim3((M * D / 4 + 255) / 256), dim3(256), 0, stream>>>(x, x0, x1, M * D / 4);

    // 2) transpose+split weights
    transpose_split_w<<<dim3(32, 32), dim3(256), 0, stream>>>(wq, Wq0, Wq1);
    transpose_split_w<<<dim3(32, 32), dim3(256), 0, stream>>>(wk, Wk0, Wk1);
    transpose_split_w<<<dim3(32, 32), dim3(256), 0, stream>>>(wv, Wv0, Wv1);

    // 3) Q = (x @ Wq) / 32, split output; K likewise unscaled; V single-product f16
    gemm_nt<3, 1><<<dim3(64, 8, 1), dim3(256), 0, stream>>>(
        x0, x1, Wq0, Wq1, nullptr, Q0, Q1, D, D, D, D, 0, 0, 0, 0.03125f);
    gemm_nt<3, 1><<<dim3(64, 8, 1), dim3(256), 0, stream>>>(
        x0, x1, Wk0, Wk1, nullptr, K0, K1, D, D, D, D, 0, 0, 0, 1.0f);
    gemm_nt<1, 2><<<dim3(64, 8, 1), dim3(256), 0, stream>>>(
        x0, nullptr, Wv0, nullptr, nullptr, V, nullptr, D, D, D, D, 0, 0, 0, 1.0f);

    // 4) V^T per batch: [2048][1024] -> [1024][2048]
    transpose_f16_k<<<dim3(32, 64, B), dim3(256), 0, stream>>>(
        V, Vt, SEQ, D, (long)SEQ * D, (long)SEQ * D);

    // 5) S = Qs @ K^T (fp32 out, already scaled via Q)
    gemm_nt<3, 0><<<dim3(16, 16, B), dim3(256), 0, stream>>>(
        Q0, Q1, K0, K1, S, nullptr, nullptr, D, D, SEQ, D,
        (long)SEQ * D, (long)SEQ * D, (long)SEQ * SEQ, 1.0f);

    // 6) P = rowsoftmax(S) as f16
    softmax_rows<<<dim3(B * SEQ), dim3(256), 0, stream>>>(S, P);

    // 7) out = P @ V  (= P @ Vt^T)
    gemm_nt<1, 0><<<dim3(16, 8, B), dim3(256), 0, stream>>>(
        P, nullptr, Vt, nullptr, out, nullptr, nullptr, SEQ, SEQ, D, SEQ,
        (long)SEQ * SEQ, (long)SEQ * D, (long)SEQ * D, 1.0f);
}

// Round 3
// 428.975 us; speedup vs baseline: 1.0466x; 1.0466x over previous
//
#include <hip/hip_runtime.h>
#include <hip/hip_bf16.h>

// HybridSelfAttention: out = softmax((xWq)(xWk)^T / sqrt(d)) (xWv)
// B=4, S=2048, D=1024, fp32 in/out.
//
// Precision: f16 hi/lo split + 3-product MFMA for xWq, xWk, QK^T (softmax is
// near-one-hot; S must be ~fp32-accurate). Plain f16 MFMA for V^T and PV.
//
// R1: LDS chunk swizzle -> bank conflicts 8.4M -> 0 (kept; free).
// R2: dispatch-count reduction (11 -> 7): Q+K fused into one GEMM over
// concatenated weights; V^T produced directly as NT-GEMM (A=Wv^T, B=x) so the
// separate f16 transpose kernel is gone; 3 weight-prep transposes merged into
// one z=3 dispatch. GEMM core untouched (m97-plateau at ~860 TF).

typedef _Float16 half8 __attribute__((ext_vector_type(8)));
typedef _Float16 half4v __attribute__((ext_vector_type(4)));
typedef float f32x4 __attribute__((ext_vector_type(4)));

#define GLOBAL_AS __attribute__((address_space(1)))
#define LDS_AS __attribute__((address_space(3)))

__device__ __forceinline__ void gll16(const _Float16* g, _Float16* l) {
    // async global->LDS, 16B per lane; LDS dest is wave-uniform base + lane*16
    __builtin_amdgcn_global_load_lds((GLOBAL_AS const void*)g, (LDS_AS void*)l, 16, 0, 0);
}

// ---------------------------------------------------------------------------
// NT GEMM: C[M,N] = (A0+A1)[M,K] * (B0+B1)[N,K]^T   (A,B row-major, K inner)
// NPROD: 1 = single product (A0*B0), 3 = split product (A0B0+A0B1+A1B0)
// OUTMODE: 0 = fp32 to Cf; 1 = f16 hi/lo split to C0,C1; 2 = f16 to C0
// Per-block scale: blocks in the lower half of gridDim.y use `scale`, upper
// half use `scale2` (lets the fused Q|K projection scale only Q by 1/32).
// Tiles: 128x128 per block (256 thr = 4 waves, 64x64 per wave), BK=32.
// mfma_f32_16x16x32_f16 fragments:
//   A/B frag: lane holds row (lane&15), 8 contiguous k at (lane>>4)*8
//   C/D frag: col = lane&15, row = (lane>>4)*4 + reg
// LDS swizzle: physical 16B chunk p of row r holds logical chunk (p-(r>>1))&3.
// ---------------------------------------------------------------------------
template <int NPROD, int OUTMODE>
__global__ __launch_bounds__(256) void gemm_nt(
    const _Float16* __restrict__ A0, const _Float16* __restrict__ A1,
    const _Float16* __restrict__ B0, const _Float16* __restrict__ B1,
    float* __restrict__ Cf, _Float16* __restrict__ C0, _Float16* __restrict__ C1,
    int lda, int ldb, int ldc, int K,
    long sA, long sB, long sC, float scale, float scale2) {
    constexpr int NTILES = (NPROD == 3) ? 4 : 2;
    __shared__ alignas(16) _Float16 smem[NTILES * 4096];  // [128][32] f16 tiles
    _Float16* sA0 = smem;
    _Float16* sB0 = smem + 4096;
    _Float16* sA1 = (NPROD == 3) ? smem + 8192 : smem;
    _Float16* sB1 = (NPROD == 3) ? smem + 12288 : smem;

    const int tid = threadIdx.x;
    const int wave = tid >> 6, lane = tid & 63;
    const int wm = (wave >> 1) * 64, wn = (wave & 1) * 64;
    const int quad = lane >> 4, r16 = lane & 15;

    const long zA = (long)blockIdx.z * sA;
    const long zB = (long)blockIdx.z * sB;
    const long zC = (long)blockIdx.z * sC;

    const float sc = (blockIdx.y * 2 < gridDim.y) ? scale : scale2;

    // staging: thread t stages 16B at LDS offset t*16 (row t>>2, phys chunk t&3).
    const int trow = tid >> 2;
    const int tcol = ((((tid & 3) - ((tid >> 3) & 3)) & 3)) * 8;
    const _Float16* gA0 = A0 + zA + (long)(blockIdx.x * 128 + trow) * lda + tcol;
    const _Float16* gB0 = B0 + zB + (long)(blockIdx.y * 128 + trow) * ldb + tcol;
    const _Float16* gA1 = (NPROD == 3) ? (A1 + zA + (long)(blockIdx.x * 128 + trow) * lda + tcol) : nullptr;
    const _Float16* gB1 = (NPROD == 3) ? (B1 + zB + (long)(blockIdx.y * 128 + trow) * ldb + tcol) : nullptr;

    f32x4 acc[4][4];
#pragma unroll
    for (int i = 0; i < 4; ++i)
#pragma unroll
        for (int j = 0; j < 4; ++j) {
            acc[i][j][0] = 0.f; acc[i][j][1] = 0.f; acc[i][j][2] = 0.f; acc[i][j][3] = 0.f;
        }

    const int ldsoff = tid * 8;  // halves; *2B = tid*16 bytes
    // read-side swizzle: physical chunk for logical chunk `quad` at row r
    const int p8 = ((quad + (r16 >> 1)) & 3) * 8;

    for (int k0 = 0; k0 < K; k0 += 32) {
        __syncthreads();  // previous iter's ds_reads done before overwrite
        gll16(gA0, sA0 + ldsoff);
        gll16(gA0 + 64 * lda, sA0 + ldsoff + 2048);
        gll16(gB0, sB0 + ldsoff);
        gll16(gB0 + 64 * ldb, sB0 + ldsoff + 2048);
        if (NPROD == 3) {
            gll16(gA1, sA1 + ldsoff);
            gll16(gA1 + 64 * lda, sA1 + ldsoff + 2048);
            gll16(gB1, sB1 + ldsoff);
            gll16(gB1 + 64 * ldb, sB1 + ldsoff + 2048);
        }
        gA0 += 32; gB0 += 32;
        if (NPROD == 3) { gA1 += 32; gB1 += 32; }
        __syncthreads();  // staging visible (compiler drains vmcnt before barrier)

        half8 a0[4], b0[4], a1[4], b1[4];
#pragma unroll
        for (int i = 0; i < 4; ++i) {
            a0[i] = *(const half8*)(sA0 + (wm + i * 16 + r16) * 32 + p8);
            b0[i] = *(const half8*)(sB0 + (wn + i * 16 + r16) * 32 + p8);
            if (NPROD == 3) {
                a1[i] = *(const half8*)(sA1 + (wm + i * 16 + r16) * 32 + p8);
                b1[i] = *(const half8*)(sB1 + (wn + i * 16 + r16) * 32 + p8);
            }
        }
#pragma unroll
        for (int i = 0; i < 4; ++i)
#pragma unroll
            for (int j = 0; j < 4; ++j) {
                acc[i][j] = __builtin_amdgcn_mfma_f32_16x16x32_f16(a0[i], b0[j], acc[i][j], 0, 0, 0);
                if (NPROD == 3) {
                    acc[i][j] = __builtin_amdgcn_mfma_f32_16x16x32_f16(a0[i], b1[j], acc[i][j], 0, 0, 0);
                    acc[i][j] = __builtin_amdgcn_mfma_f32_16x16x32_f16(a1[i], b0[j], acc[i][j], 0, 0, 0);
                }
            }
    }

    // epilogue: C/D layout col=lane&15, row=quad*4+reg
    const int crow0 = blockIdx.x * 128 + wm + quad * 4;
    const int ccol0 = blockIdx.y * 128 + wn + r16;
#pragma unroll
    for (int i = 0; i < 4; ++i)
#pragma unroll
        for (int j = 0; j < 4; ++j)
#pragma unroll
            for (int r = 0; r < 4; ++r) {
                long off = zC + (long)(crow0 + i * 16 + r) * ldc + (ccol0 + j * 16);
                float v = acc[i][j][r] * sc;
                if (OUTMODE == 0) {
                    Cf[off] = v;
                } else if (OUTMODE == 2) {
                    C0[off] = (_Float16)v;
                } else {
                    _Float16 h = (_Float16)v;
                    C0[off] = h;
                    C1[off] = (_Float16)(v - (float)h);
                }
            }
}

// ---------------------------------------------------------------------------
// x fp32 -> hi/lo f16 split (vectorized x4)
// ---------------------------------------------------------------------------
__global__ __launch_bounds__(256) void split_x(const float* __restrict__ in,
                                               _Float16* __restrict__ o0,
                                               _Float16* __restrict__ o1, long n4) {
    long i = (long)blockIdx.x * 256 + threadIdx.x;
    if (i >= n4) return;
    float4 v = ((const float4*)in)[i];
    float a[4] = {v.x, v.y, v.z, v.w};
    half4v h, l;
#pragma unroll
    for (int c = 0; c < 4; ++c) {
        h[c] = (_Float16)a[c];
        l[c] = (_Float16)(a[c] - (float)h[c]);
    }
    ((half4v*)o0)[i] = h;
    ((half4v*)o1)[i] = l;
}

// ---------------------------------------------------------------------------
// All three weights in one dispatch (z=0:Wq, 1:Wk, 2:Wv).
// W[1024][1024] fp32 -> W^T hi/lo f16. Wq^T/Wk^T land stacked in one
// [2048][1024] buffer (rows 0..1023 = Wq^T, 1024..2047 = Wk^T).
// ---------------------------------------------------------------------------
__global__ __launch_bounds__(256) void transpose_split_w3(
    const float* __restrict__ wq, const float* __restrict__ wk,
    const float* __restrict__ wv,
    _Float16* __restrict__ qk0, _Float16* __restrict__ qk1,
    _Float16* __restrict__ v0, _Float16* __restrict__ v1) {
    const int z = blockIdx.z;
    const float* in = (z == 0) ? wq : (z == 1) ? wk : wv;
    _Float16* o0 = (z == 0) ? qk0 : (z == 1) ? qk0 + 1024 * 1024 : v0;
    _Float16* o1 = (z == 0) ? qk1 : (z == 1) ? qk1 + 1024 * 1024 : v1;

    __shared__ float t[32][33];
    const int c0 = blockIdx.x * 32, r0 = blockIdx.y * 32;
    const int tx = threadIdx.x & 31, ty = threadIdx.x >> 5;
#pragma unroll
    for (int i = 0; i < 32; i += 8)
        t[ty + i][tx] = in[(long)(r0 + ty + i) * 1024 + c0 + tx];
    __syncthreads();
#pragma unroll
    for (int i = 0; i < 32; i += 8) {
        float v = t[tx][ty + i];
        _Float16 h = (_Float16)v;
        long o = (long)(c0 + ty + i) * 1024 + r0 + tx;
        o0[o] = h;
        o1[o] = (_Float16)(v - (float)h);
    }
}

// ---------------------------------------------------------------------------
// row softmax: S fp32 [8192][2048] -> P f16, one block per row (vectorized)
// ---------------------------------------------------------------------------
__global__ __launch_bounds__(256) void softmax_rows(const float* __restrict__ S,
                                                    _Float16* __restrict__ P) {
    const int n = 2048;
    const long base = (long)blockIdx.x * n;
    const float4* row4 = (const float4*)(S + base);
    const int tid = threadIdx.x;
    const int wave = tid >> 6;

    float4 v0 = row4[tid * 2];
    float4 v1 = row4[tid * 2 + 1];
    float v[8] = {v0.x, v0.y, v0.z, v0.w, v1.x, v1.y, v1.z, v1.w};
    float lm = -3.4e38f;
#pragma unroll
    for (int t = 0; t < 8; ++t) lm = fmaxf(lm, v[t]);
#pragma unroll
    for (int o = 32; o > 0; o >>= 1) lm = fmaxf(lm, __shfl_xor(lm, o));
    __shared__ float redm[4];
    __shared__ float reds[4];
    if ((tid & 63) == 0) redm[wave] = lm;
    __syncthreads();
    lm = fmaxf(fmaxf(redm[0], redm[1]), fmaxf(redm[2], redm[3]));

    float e[8];
    float ls = 0.f;
#pragma unroll
    for (int t = 0; t < 8; ++t) {
        e[t] = __expf(v[t] - lm);
        ls += e[t];
    }
#pragma unroll
    for (int o = 32; o > 0; o >>= 1) ls += __shfl_xor(ls, o);
    if ((tid & 63) == 0) reds[wave] = ls;
    __syncthreads();
    ls = reds[0] + reds[1] + reds[2] + reds[3];
    const float inv = 1.f / ls;
    half8 p;
#pragma unroll
    for (int t = 0; t < 8; ++t) p[t] = (_Float16)(e[t] * inv);
    ((half8*)(P + base))[tid] = p;
}

// ---------------------------------------------------------------------------
extern "C" void kernel_launch(void* const* d_in, const int* in_sizes, int n_in,
                              void* d_out, int out_size, void* d_ws, size_t ws_size,
                              hipStream_t stream) {
    (void)in_sizes; (void)n_in; (void)out_size; (void)ws_size;
    const float* x = (const float*)d_in[0];
    const float* wq = (const float*)d_in[1];
    const float* wk = (const float*)d_in[2];
    const float* wv = (const float*)d_in[3];
    float* out = (float*)d_out;
    char* ws = (char*)d_ws;

    const long MB = 1l << 20;
    // ws layout (188 MB):
    _Float16* Wqk0 = (_Float16*)(ws + 0 * MB);   // [2048][1024] 4 MB
    _Float16* Wqk1 = (_Float16*)(ws + 4 * MB);   // 4 MB
    _Float16* Wv0  = (_Float16*)(ws + 8 * MB);   // 2 MB
    _Float16* Wv1  = (_Float16*)(ws + 10 * MB);  // 2 MB (unused by NPROD=1 path)
    _Float16* x0   = (_Float16*)(ws + 12 * MB);  // 16 MB
    _Float16* x1   = (_Float16*)(ws + 28 * MB);  // 16 MB
    _Float16* P    = (_Float16*)(ws + 12 * MB);  // 32 MB, reuses dead x0/x1
    _Float16* QK0  = (_Float16*)(ws + 44 * MB);  // [8192][2048] 32 MB
    _Float16* QK1  = (_Float16*)(ws + 76 * MB);  // 32 MB
    _Float16* Vt   = (_Float16*)(ws + 108 * MB); // [1024][8192] 16 MB
    float*    S    = (float*)(ws + 124 * MB);    // 64 MB

    const int B = 4, SEQ = 2048, D = 1024;
    const long M = (long)B * SEQ;  // 8192
    const long ssq = (long)SEQ * SEQ;  // per-batch S stride

    // 1) split x into f16 hi/lo
    split_x<<<dim3((M * D / 4 + 255) / 256), dim3(256), 0, stream>>>(x, x0, x1, M * D / 4);

    // 2) transpose+split all weights (one dispatch)
    transpose_split_w3<<<dim3(32, 32, 3), dim3(256), 0, stream>>>(
        wq, wk, wv, Wqk0, Wqk1, Wv0, Wv1);

    // 3) fused Q|K projection: QK[m][n] (n<1024 -> Q/32, n>=1024 -> K), split out
    gemm_nt<3, 1><<<dim3(64, 16, 1), dim3(256), 0, stream>>>(
        x0, x1, Wqk0, Wqk1, nullptr, QK0, QK1, D, D, 2 * D, D,
        0, 0, 0, 0.03125f, 1.0f);

    // 4) V^T directly: Vt[e][m] = sum_d Wv^T[e][d] * x[m][d]  (NT, A=Wv^T, B=x)
    gemm_nt<1, 2><<<dim3(8, 64, 1), dim3(256), 0, stream>>>(
        Wv0, nullptr, x0, nullptr, nullptr, Vt, nullptr, D, D, (int)M, D,
        0, 0, 0, 1.0f, 1.0f);

    // 5) S = Qs @ K^T (fp32, scaling already folded into Q)
    gemm_nt<3, 0><<<dim3(16, 16, B), dim3(256), 0, stream>>>(
        QK0, QK1, QK0 + D, QK1 + D, S, nullptr, nullptr, 2 * D, 2 * D, SEQ, D,
        (long)SEQ * 2 * D, (long)SEQ * 2 * D, ssq, 1.0f, 1.0f);

    // 6) P = rowsoftmax(S) as f16
    softmax_rows<<<dim3(B * SEQ), dim3(256), 0, stream>>>(S, P);

    // 7) out = P @ V = P @ (Vt batch-view)^T ; Vt batch b = cols b*2048..
    gemm_nt<1, 0><<<dim3(16, 8, B), dim3(256), 0, stream>>>(
        P, nullptr, Vt, nullptr, out, nullptr, nullptr, SEQ, (int)M, D, SEQ,
        ssq, (long)SEQ, (long)SEQ * D, 1.0f, 1.0f);
}